// Round 17
// baseline (222.858 us; speedup 1.0000x reference)
//
#include <hip/hip_runtime.h>
#include <hip/hip_bf16.h>

// Problem constants
#define BB 2
#define SS 2048
#define DD 1024
#define HH 16
#define DHH 64

#define SCLOG2E 0.045084221f      // (1/sqrt(1024)) * log2(e) -- folded into Wt_q

typedef unsigned short u16;
typedef unsigned int   u32;
typedef __bf16 bf16_t;
typedef bf16_t bf16x8 __attribute__((ext_vector_type(8)));
typedef u16    u16x8  __attribute__((ext_vector_type(8)));
typedef u32    u32x4v __attribute__((ext_vector_type(4)));
typedef float  f32x4  __attribute__((ext_vector_type(4)));

#define MFMA(a,b,c) __builtin_amdgcn_mfma_f32_16x16x32_bf16(a,b,c,0,0,0)

// swizzles: 16B chunk c of a row stored at c ^ (row & mask). Same XOR on read.
#define SW(c,r)  ((c) ^ ((r) & 7))   // 64-elem (128B) rows
#define SW3(c,r) ((c) ^ ((r) & 3))   // 32-elem (64B) rows

typedef __attribute__((address_space(1))) const unsigned int as1_u32;
typedef __attribute__((address_space(3))) unsigned int as3_u32;

__device__ __forceinline__ void gld16(const void* g, void* l){
  __builtin_amdgcn_global_load_lds((as1_u32*)g, (as3_u32*)l, 16, 0, 0);
}

__device__ __forceinline__ u16 f2bf(float f){           // cold paths
  u32 u = __builtin_bit_cast(u32, f);
  u32 r = (u + 0x7fffu + ((u >> 16) & 1u)) >> 16;
  return (u16)r;
}
__device__ __forceinline__ u16 nbf(float f){            // hot path: native cvt
  bf16_t b = (bf16_t)f;
  return __builtin_bit_cast(u16, b);
}
__device__ __forceinline__ float bf2f(u16 v){
  u32 u = ((u32)v) << 16;
  return __builtin_bit_cast(float, u);
}
__device__ __forceinline__ bf16x8 ldb8(const u16* p){
  return __builtin_bit_cast(bf16x8, *(const u16x8*)p);
}

// stage 64 rows x 64 bf16 (128B/row) = 8KB. 2 gld16/thread.
__device__ __forceinline__ void stage64(const u16* __restrict__ g0, int stride,
                                        u16* lds0, int tid){
  int w = tid >> 6, lane = tid & 63;
  #pragma unroll
  for (int j = 0; j < 2; j++){
    int slot = j*256 + w*64 + lane;
    int row = slot >> 3, c = slot & 7;
    gld16(g0 + (size_t)row*stride + (SW(c,row) << 3),
          lds0 + (size_t)(j*256 + w*64)*8);
  }
}

// stage 128 rows x 32 bf16 (64B/row) = 8KB. 2 gld16/thread.
__device__ __forceinline__ void stage32(const u16* __restrict__ g0, int stride,
                                        u16* lds0, int tid){
  int w = tid >> 6, lane = tid & 63;
  #pragma unroll
  for (int j = 0; j < 2; j++){
    int slot = j*256 + w*64 + lane;
    int row = slot >> 2, c = slot & 3;
    gld16(g0 + (size_t)row*stride + (SW3(c,row) << 3),
          lds0 + (size_t)(j*256 + w*64)*8);
  }
}

// ---------------- mask dtype detection ----------------
__global__ __launch_bounds__(256) void detect_mask(const u32* mw, u32* flag){
  __shared__ int fBig, fFloat;
  if (threadIdx.x == 0){ fBig = 0; fFloat = 0; }
  __syncthreads();
  for (int i = threadIdx.x; i < 4096; i += 256){
    u32 w = mw[i];
    if (w == 0x3f800000u) fFloat = 1;
    else if (w > 1u) fBig = 1;
  }
  __syncthreads();
  if (threadIdx.x == 0) *flag = fFloat ? 2u : (fBig ? 1u : 0u);
}

// e0 = ELEMENT index; packs 32 consecutive mask elements into one bit-word.
__device__ __forceinline__ u32 pack32(const void* mask, u32 f, size_t e0){
  u32 bits = 0;
  if (f == 1u){
    const uchar4* mb = (const uchar4*)((const unsigned char*)mask + e0);
    #pragma unroll
    for (int j = 0; j < 8; j++){
      uchar4 v = mb[j];
      bits |= (v.x?1u:0u) << (4*j)   | (v.y?1u:0u) << (4*j+1)
            | (v.z?1u:0u) << (4*j+2) | (v.w?1u:0u) << (4*j+3);
    }
  } else if (f == 0u){
    const int4* mi = (const int4*)((const int*)mask + e0);
    #pragma unroll
    for (int j = 0; j < 8; j++){
      int4 v = mi[j];
      bits |= (v.x?1u:0u) << (4*j)   | (v.y?1u:0u) << (4*j+1)
            | (v.z?1u:0u) << (4*j+2) | (v.w?1u:0u) << (4*j+3);
    }
  } else {
    const float4* mf = (const float4*)((const float*)mask + e0);
    #pragma unroll
    for (int j = 0; j < 8; j++){
      float4 v = mf[j];
      bits |= (v.x!=0.f?1u:0u) << (4*j)   | (v.y!=0.f?1u:0u) << (4*j+1)
            | (v.z!=0.f?1u:0u) << (4*j+2) | (v.w!=0.f?1u:0u) << (4*j+3);
    }
  }
  return bits;
}

// ---------------- merged prep: cvt3 + prep_w + pack_maskT in one dispatch ----
// blocks [0,6144): f32->bf16 convert of query/key/value (2048 blocks each)
// blocks [6144,7168): weight transpose (1024 blocks; z=id>>8)
// blocks [7168,7424): mask bit-pack transposed (256 blocks)
__global__ __launch_bounds__(256) void prep_all(
    const float* __restrict__ qs, const float* __restrict__ ks,
    const float* __restrict__ vs,
    u16* __restrict__ Aq, u16* __restrict__ Ak, u16* __restrict__ Av,
    const float* __restrict__ W0, const float* __restrict__ W1,
    const float* __restrict__ W2, const float* __restrict__ W3,
    u16* __restrict__ Wt,
    const void* __restrict__ mask, const u32* __restrict__ flag,
    u32* __restrict__ pmT){
  __shared__ float shmem[64*65];
  int bx = blockIdx.x;
  if (bx < 6144){
    // cvt role
    int zc = bx >> 11, xb = bx & 2047;
    const float* s = zc == 0 ? qs : (zc == 1 ? ks : vs);
    u16*         d = zc == 0 ? Aq : (zc == 1 ? Ak : Av);
    size_t i = ((size_t)xb*256 + threadIdx.x) * 8;
    const float4* p = (const float4*)(s + i);
    float4 x = p[0], y = p[1];
    u16x8 u;
    u[0]=f2bf(x.x); u[1]=f2bf(x.y); u[2]=f2bf(x.z); u[3]=f2bf(x.w);
    u[4]=f2bf(y.x); u[5]=f2bf(y.y); u[6]=f2bf(y.z); u[7]=f2bf(y.w);
    *(u16x8*)(d + i) = u;
  } else if (bx < 7168){
    // prep_w role: f32[k][n] -> bf16 Wt[n][k]; W_q pre-scaled by SCLOG2E
    int id = bx - 6144;
    int z = id >> 8, rem = id & 255;
    int kb = (rem & 15) * 64, nb = (rem >> 4) * 64;
    const float* Ws[4] = {W0, W1, W2, W3};
    const float* W = Ws[z];
    float scl = (z == 0) ? SCLOG2E : 1.0f;
    u16* O = Wt + (size_t)z * DD * DD;
    float (*tile)[65] = (float(*)[65])shmem;
    int col = threadIdx.x & 63, rr = threadIdx.x >> 6;
    #pragma unroll
    for (int i = 0; i < 16; i++){
      int row = i*4 + rr;
      tile[row][col] = W[(size_t)(kb+row)*DD + nb + col];
    }
    __syncthreads();
    #pragma unroll
    for (int i = 0; i < 16; i++){
      int row = i*4 + rr;
      O[(size_t)(nb+row)*DD + kb + col] = f2bf(tile[col][row] * scl);
    }
  } else {
    // pack role: pmT[b][kw][q], 16q x 64kw tile per block
    int id = bx - 7168;
    int q0 = (id & 127) * 16, b = id >> 7;
    u32 f = *flag;
    u32 (*tile)[65] = (u32(*)[65])shmem;
    int kw = threadIdx.x & 63, qr = threadIdx.x >> 6;
    #pragma unroll
    for (int i = 0; i < 4; i++){
      int row = i*4 + qr;
      size_t e0 = ((size_t)(b*SS + q0 + row))*SS + kw*32;
      tile[row][kw] = pack32(mask, f, e0);
    }
    __syncthreads();
    int q = threadIdx.x & 15, kw0 = threadIdx.x >> 4;
    #pragma unroll
    for (int i = 0; i < 4; i++){
      int kww = i*16 + kw0;
      pmT[((size_t)b*64 + kww)*SS + q0 + q] = tile[q][kww];
    }
  }
}

// ---------------- staged GEMM, BK=32: C[M][1024] = A @ Bt^T ------
// 128x128 tile, 4 waves (2x2 of 64x64), 32 KB LDS double-buffered.
// mode 0: bf16 Cb; 1: Cb + f32 permuted [B][H][S][DH]; 2: f32 flat only.
struct GA { const u16* A; const u16* Bt; u16* Cb; float* Co; int mode; };

__global__ __launch_bounds__(256) void gemm32(GA a0, GA a1, GA a2){
  GA ga = blockIdx.z == 0 ? a0 : (blockIdx.z == 1 ? a1 : a2);
  __shared__ u16 As[2][128*32];
  __shared__ u16 Bs[2][128*32];
  int mb = blockIdx.x * 128, nb = blockIdx.y * 128;
  int tid = threadIdx.x, w = tid >> 6, lane = tid & 63, ln = lane & 15, g = lane >> 4;
  int wr = w >> 1, wc = w & 1;
  f32x4 acc[4][4];
  #pragma unroll
  for (int i = 0; i < 4; i++)
    #pragma unroll
    for (int j = 0; j < 4; j++) acc[i][j] = (f32x4){0,0,0,0};

  stage32(ga.A  + (size_t)mb*DD, DD, As[0], tid);
  stage32(ga.Bt + (size_t)nb*DD, DD, Bs[0], tid);
  __syncthreads();
  int buf = 0;
  for (int t = 0; t < 32; t++){
    if (t < 31){
      stage32(ga.A  + (size_t)mb*DD + (t+1)*32, DD, As[buf^1], tid);
      stage32(ga.Bt + (size_t)nb*DD + (t+1)*32, DD, Bs[buf^1], tid);
    }
    bf16x8 av[4], bv[4];
    #pragma unroll
    for (int mf = 0; mf < 4; mf++){
      int row = wr*64 + mf*16 + ln;
      av[mf] = ldb8(&As[buf][row*32 + (SW3(g,row) << 3)]);
    }
    #pragma unroll
    for (int nf = 0; nf < 4; nf++){
      int row = wc*64 + nf*16 + ln;
      bv[nf] = ldb8(&Bs[buf][row*32 + (SW3(g,row) << 3)]);
    }
    #pragma unroll
    for (int mf = 0; mf < 4; mf++)
      #pragma unroll
      for (int nf = 0; nf < 4; nf++)
        acc[mf][nf] = MFMA(av[mf], bv[nf], acc[mf][nf]);
    __syncthreads();
    buf ^= 1;
  }
  #pragma unroll
  for (int mf = 0; mf < 4; mf++){
    #pragma unroll
    for (int nf = 0; nf < 4; nf++){
      #pragma unroll
      for (int r = 0; r < 4; r++){
        int row = mb + wr*64 + mf*16 + g*4 + r;
        int col = nb + wc*64 + nf*16 + ln;
        float v = acc[mf][nf][r];
        if (ga.mode != 2)
          ga.Cb[(size_t)row*DD + col] = f2bf(v);
        if (ga.mode == 1){
          int b_ = row >> 11, s_ = row & (SS-1);
          int h_ = col >> 6,  d_ = col & 63;
          ga.Co[(((size_t)(b_*HH + h_))*SS + s_)*DHH + d_] = v;
        }
        if (ga.mode == 2)
          ga.Co[(size_t)row*DD + col] = v;
      }
    }
  }
}

// ---------------- pass 1: column softmax denominators c[k] + fused V scale ---
// 128-k blocks, 4 waves x 32 k; Q staged in LDS, double-buffered; XCD swizzle;
// transposed mask pmT. Epilogue: broadcast c via LDS, then scale_v inline for
// this block's own 128 k rows of V (LDS transpose + pi k-permutation).
__global__ __launch_bounds__(256) void pass1_sv(const u16* __restrict__ Qb,
                                                const u16* __restrict__ Kb,
                                                const u32* __restrict__ pmT,
                                                const u16* __restrict__ Vb,
                                                u16* __restrict__ Vt){
  __shared__ u16 Qst[2][64*64];
  __shared__ float cs[128];
  // bijective XCD swizzle: nwg = 16*16*2 = 512, chunk = 64
  int flat = blockIdx.x + (SS/128)*(blockIdx.y + HH*blockIdx.z);
  int sw = (flat & 7)*64 + (flat >> 3);
  int kblk = (sw & 15) * 128;
  int rest = sw >> 4;
  int h = rest & 15, b = rest >> 4;
  int tid = threadIdx.x, w = tid >> 6, lane = tid & 63, ln = lane & 15, g = lane >> 4;
  bf16x8 kf[2][2];
  #pragma unroll
  for (int f = 0; f < 2; f++){
    const u16* kp = Kb + ((size_t)b*SS + kblk + w*32 + f*16 + ln)*DD + h*DHH + g*8;
    kf[f][0] = ldb8(kp); kf[f][1] = ldb8(kp + 32);
  }
  float cr[2][4] = {{0,0,0,0},{0,0,0,0}};

  stage64(Qb + ((size_t)b*SS)*DD + h*DHH, DD, Qst[0], tid);
  __syncthreads();
  int buf = 0;
  const u32* pmw = pmT + ((size_t)b*64 + (kblk >> 5) + w)*SS;
  for (int t = 0; t < 32; t++){
    if (t < 31) stage64(Qb + ((size_t)b*SS + (t+1)*64)*DD + h*DHH, DD, Qst[buf^1], tid);
    #pragma unroll
    for (int qc = 0; qc < 4; qc++){
      int row = qc*16 + ln;
      bf16x8 b0 = ldb8(&Qst[buf][row*64 + (SW(g,  row) << 3)]);
      bf16x8 b1 = ldb8(&Qst[buf][row*64 + (SW(g+4,row) << 3)]);
      int q = t*64 + qc*16 + ln;
      u32 mw = pmw[q];
      #pragma unroll
      for (int f = 0; f < 2; f++){
        f32x4 sf = {0,0,0,0};
        sf = MFMA(kf[f][0], b0, sf);
        sf = MFMA(kf[f][1], b1, sf);
        #pragma unroll
        for (int r = 0; r < 4; r++){
          float e = __builtin_amdgcn_exp2f(sf[r]);
          cr[f][r] += ((mw >> (f*16 + g*4 + r)) & 1u) ? 0.f : e;
        }
      }
    }
    __syncthreads();
    buf ^= 1;
  }
  #pragma unroll
  for (int f = 0; f < 2; f++)
    #pragma unroll
    for (int r = 0; r < 4; r++){
      #pragma unroll
      for (int msk = 1; msk < 16; msk <<= 1)
        cr[f][r] += __shfl_xor(cr[f][r], msk, 64);
    }
  if (ln == 0){
    #pragma unroll
    for (int f = 0; f < 2; f++)
      #pragma unroll
      for (int r = 0; r < 4; r++)
        cs[w*32 + f*16 + g*4 + r] = cr[f][r];
  }
  __syncthreads();

  // ---- fused scale_v: this block's 128 k rows (2 chunks of 64) ----
  u16 (*vt)[72] = (u16(*)[72])&Qst[0][0];   // 9.2 KB alias, Qst dead
  int col = tid & 63, rr = tid >> 6;
  #pragma unroll 1
  for (int ch = 0; ch < 2; ch++){
    int st = kblk + ch*64;
    #pragma unroll
    for (int i = 0; i < 16; i++){
      int row = i*4 + rr;
      float inv = 1.0f / cs[ch*64 + row];
      float v = bf2f(Vb[((size_t)b*SS + st + row)*DD + h*DHH + col]);
      vt[row][col] = f2bf(v * inv);
    }
    __syncthreads();
    int pc = (col & 32) + ((col >> 2) & 3)*8 + ((col >> 4) & 1)*4 + (col & 3);
    #pragma unroll
    for (int i = 0; i < 16; i++){
      int row = i*4 + rr;   // row = d index
      Vt[(((size_t)b*HH + h)*DHH + row)*SS + st + pc] = vt[col][row];
    }
    __syncthreads();
  }
}

// ---------------- pass 2: hidden = exp2(S) @ (V/c) ----------------
// 128 q / 4 waves x 32 q (2 frags). Triple-buffered K,V (48 KB LDS).
// Software pipeline: body t = { sync; stage(t+2); QK(t+1)->pkNext; PV(t)<-pkCur }
// so exp2/pack (VALU) of tile t+1 overlaps PV MFMAs of tile t.
// P in registers (S^T = mfma(K,Q)); transposed mask pmT (coalesced, ptr-bumped).
#define P2_QK(PMP, NXT, KP) { \
  u32 _ml[2], _mh[2]; \
  _Pragma("unroll") for (int f = 0; f < 2; f++){ \
    _ml[f] = (PMP)[f*16]; \
    _mh[f] = (PMP)[SS + f*16]; \
  } \
  _Pragma("unroll") for (int kc = 0; kc < 4; kc++){ \
    bf16x8 a0 = ldb8(&KP[koff[kc][0]]); \
    bf16x8 a1 = ldb8(&KP[koff[kc][1]]); \
    _Pragma("unroll") for (int f = 0; f < 2; f++){ \
      f32x4 sf = {0,0,0,0}; \
      sf = MFMA(a0, qf[f][0], sf); \
      sf = MFMA(a1, qf[f][1], sf); \
      u32 mword = (kc < 2) ? _ml[f] : _mh[f]; \
      int msh = (kc & 1) * 16 + g*4; \
      float p0 = ((mword >> (msh+0)) & 1u) ? 0.f : __builtin_amdgcn_exp2f(sf[0]); \
      float p1 = ((mword >> (msh+1)) & 1u) ? 0.f : __builtin_amdgcn_exp2f(sf[1]); \
      float p2 = ((mword >> (msh+2)) & 1u) ? 0.f : __builtin_amdgcn_exp2f(sf[2]); \
      float p3 = ((mword >> (msh+3)) & 1u) ? 0.f : __builtin_amdgcn_exp2f(sf[3]); \
      NXT[f][kc*2]   = (u32)nbf(p0) | ((u32)nbf(p1) << 16); \
      NXT[f][kc*2+1] = (u32)nbf(p2) | ((u32)nbf(p3) << 16); \
    } \
  } }

#define P2_PV(CUR, VP) \
  _Pragma("unroll") for (int kh = 0; kh < 2; kh++){ \
    bf16x8 pa[2]; \
    _Pragma("unroll") for (int f = 0; f < 2; f++) \
      pa[f] = __builtin_bit_cast(bf16x8, \
        (u32x4v){CUR[f][4*kh], CUR[f][4*kh+1], CUR[f][4*kh+2], CUR[f][4*kh+3]}); \
    _Pragma("unroll") for (int df = 0; df < 4; df++){ \
      bf16x8 bv = ldb8(&VP[voff[kh][df]]); \
      _Pragma("unroll") for (int f = 0; f < 2; f++) \
        acc[f][df] = MFMA(pa[f], bv, acc[f][df]); \
    } \
  }

#define P2_BODY(TT, CUR, NXT) \
  __syncthreads(); \
  if ((TT) < 30){ \
    stage64(Kg + (size_t)((TT)+2)*64*DD, DD, K2, tid); \
    stage64(Vth + ((TT)+2)*64,           SS, V2, tid); \
  } \
  if ((TT) < 31) P2_QK(pmq, NXT, K1) \
  P2_PV(CUR, V0) \
  { u16* _tp=K0; K0=K1; K1=K2; K2=_tp; _tp=V0; V0=V1; V1=V2; V2=_tp; pmq += 2*SS; }

__global__ __launch_bounds__(256) void pass2_pv(const u16* __restrict__ Qb,
                                                const u16* __restrict__ Kb,
                                                const u16* __restrict__ Vt,
                                                const u32* __restrict__ pmT,
                                                u16* __restrict__ Hb){
  __shared__ u16 Kst[3][64*64];
  __shared__ u16 Vst[3][64*64];
  // bijective XCD swizzle: nwg = 16*16*2 = 512, chunk = 64
  int flat = blockIdx.x + (SS/128)*(blockIdx.y + HH*blockIdx.z);
  int sw = (flat & 7)*64 + (flat >> 3);
  int qt = (sw & 15) * 128;
  int rest = sw >> 4;
  int h = rest & 15, b = rest >> 4;
  int tid = threadIdx.x, w = tid >> 6, lane = tid & 63, ln = lane & 15, g = lane >> 4;
  bf16x8 qf[2][2];
  #pragma unroll
  for (int f = 0; f < 2; f++){
    const u16* qp = Qb + ((size_t)b*SS + qt + w*32 + f*16 + ln)*DD + h*DHH + g*8;
    qf[f][0] = ldb8(qp); qf[f][1] = ldb8(qp + 32);
  }
  f32x4 acc[2][4];
  #pragma unroll
  for (int f = 0; f < 2; f++)
    #pragma unroll
    for (int d = 0; d < 4; d++) acc[f][d] = (f32x4){0,0,0,0};

  const u16* Kg  = Kb + ((size_t)b*SS)*DD + h*DHH;
  const u16* Vth = Vt + ((size_t)b*HH + h)*DHH*SS;
  const u32* pmq = pmT + (size_t)b*64*SS + (qt + w*32 + ln);

  // t-invariant LDS offsets (hoisted addressing)
  int koff[4][2], voff[2][4];
  #pragma unroll
  for (int kc = 0; kc < 4; kc++){
    int row = kc*16 + ln;
    koff[kc][0] = row*64 + (SW(g,  row) << 3);
    koff[kc][1] = row*64 + (SW(g+4,row) << 3);
  }
  #pragma unroll
  for (int kh = 0; kh < 2; kh++)
    #pragma unroll
    for (int df = 0; df < 4; df++){
      int row = df*16 + ln;
      voff[kh][df] = row*64 + (SW(kh*4+g, row) << 3);
    }

  u16 *K0=&Kst[0][0], *K1=&Kst[1][0], *K2=&Kst[2][0];
  u16 *V0=&Vst[0][0], *V1=&Vst[1][0], *V2=&Vst[2][0];
  u32 pkA[2][8], pkB[2][8];

  stage64(Kg,  DD, K0, tid);
  stage64(Vth, SS, V0, tid);
  __syncthreads();
  P2_QK(pmq, pkA, K0)
  pmq += 2*SS;                   // now points at tile-1 mask words
  stage64(Kg + 64*DD, DD, K1, tid);
  stage64(Vth + 64,   SS, V1, tid);

  #pragma unroll 1
  for (int t = 0; t < 32; t += 2){
    P2_BODY(t,   pkA, pkB)
    P2_BODY(t+1, pkB, pkA)
  }

  #pragma unroll
  for (int f = 0; f < 2; f++)
    #pragma unroll
    for (int df = 0; df < 4; df++)
      #pragma unroll
      for (int r = 0; r < 4; r++){
        int row = qt + w*32 + f*16 + g*4 + r;
        int col = h*DHH + df*16 + ln;
        Hb[((size_t)b*SS + row)*DD + col] = f2bf(acc[f][df][r]);
      }
}

extern "C" void kernel_launch(void* const* d_in, const int* in_sizes, int n_in,
                              void* d_out, int out_size, void* d_ws, size_t ws_size,
                              hipStream_t stream){
  (void)in_sizes; (void)n_in; (void)out_size; (void)ws_size;
  const float* query = (const float*)d_in[0];
  const float* key   = (const float*)d_in[1];
  const float* value = (const float*)d_in[2];
  const void*  mask  = d_in[3];
  const float* W_q = (const float*)d_in[4];
  const float* W_k = (const float*)d_in[5];
  const float* W_v = (const float*)d_in[6];
  const float* W_o = (const float*)d_in[7];

  float* out   = (float*)d_out;
  float* out_h = out;                                  // [B,S,1024]
  float* out_k = out   + (size_t)BB*HH*SS*DHH;         // [B,H,S,DH]
  float* out_v = out_k + (size_t)BB*HH*SS*DHH;

  char* w = (char*)d_ws;
  u16*   Wt  = (u16*)(w);                      // 4 x [1024][1024] bf16 = 8 MB
  u16*   Av  = (u16*)(w + (size_t)( 8u<<20));  // bf16 value input; later Hb
  u16*   Qb  = (u16*)(w + (size_t)(16u<<20));
  u16*   Kb  = (u16*)(w + (size_t)(24u<<20));
  u16*   Vb  = (u16*)(w + (size_t)(32u<<20));
  u16*   Vt  = (u16*)(w + (size_t)(40u<<20));  // [B][H][DH][S] bf16, k-permuted
  u32*   pmT = (u32*)(w + (size_t)(48u<<20) + (512u<<10));   // 1 MB transposed mask
  u32*   flag= (u32*)(w + (size_t)(48u<<20) + (1664u<<10));
  u16*   Hb  = Av;                             // alias: Av dead after projections
  // bf16 query/key inputs staged inside out_h (dead until final GEMM rewrites it)
  u16*   Aq  = (u16*)out_h;
  u16*   Ak  = Aq + (size_t)BB*SS*DD;

  detect_mask<<<dim3(1), dim3(256), 0, stream>>>((const u32*)mask, flag);
  prep_all<<<dim3(7424), dim3(256), 0, stream>>>(query, key, value, Aq, Ak, Av,
                                                 W_q, W_k, W_v, W_o, Wt,
                                                 mask, flag, pmT);

  GA gq = { Aq, Wt,             Qb, nullptr, 0 };
  GA gk = { Ak, Wt + 1*1048576, Kb, out_k,   1 };
  GA gv = { Av, Wt + 2*1048576, Vb, out_v,   1 };
  gemm32<<<dim3(32,8,3), dim3(256), 0, stream>>>(gq, gk, gv);

  pass1_sv<<<dim3(SS/128, HH, BB), dim3(256), 0, stream>>>(Qb, Kb, pmT, Vb, Vt);
  pass2_pv<<<dim3(SS/128, HH, BB), dim3(256), 0, stream>>>(Qb, Kb, Vt, pmT, Hb);

  GA go = { Hb, Wt + 3*1048576, nullptr, out_h, 2 };
  gemm32<<<dim3(32,8,1), dim3(256), 0, stream>>>(go, go, go);
}

// Round 18
// 212.328 us; speedup vs baseline: 1.0496x; 1.0496x over previous
//
#include <hip/hip_runtime.h>
#include <hip/hip_bf16.h>

// Problem constants
#define BB 2
#define SS 2048
#define DD 1024
#define HH 16
#define DHH 64

#define SCLOG2E 0.045084221f      // (1/sqrt(1024)) * log2(e) -- folded into Wt_q

typedef unsigned short u16;
typedef unsigned int   u32;
typedef __bf16 bf16_t;
typedef bf16_t bf16x8 __attribute__((ext_vector_type(8)));
typedef u16    u16x8  __attribute__((ext_vector_type(8)));
typedef u32    u32x4v __attribute__((ext_vector_type(4)));
typedef float  f32x4  __attribute__((ext_vector_type(4)));

#define MFMA(a,b,c) __builtin_amdgcn_mfma_f32_16x16x32_bf16(a,b,c,0,0,0)

// swizzles: 16B chunk c of a row stored at c ^ (row & mask). Same XOR on read.
#define SW(c,r)  ((c) ^ ((r) & 7))   // 64-elem (128B) rows
#define SW3(c,r) ((c) ^ ((r) & 3))   // 32-elem (64B) rows

typedef __attribute__((address_space(1))) const unsigned int as1_u32;
typedef __attribute__((address_space(3))) unsigned int as3_u32;

__device__ __forceinline__ void gld16(const void* g, void* l){
  __builtin_amdgcn_global_load_lds((as1_u32*)g, (as3_u32*)l, 16, 0, 0);
}

__device__ __forceinline__ u16 f2bf(float f){           // cold paths
  u32 u = __builtin_bit_cast(u32, f);
  u32 r = (u + 0x7fffu + ((u >> 16) & 1u)) >> 16;
  return (u16)r;
}
__device__ __forceinline__ u16 nbf(float f){            // hot path: native cvt
  bf16_t b = (bf16_t)f;
  return __builtin_bit_cast(u16, b);
}
__device__ __forceinline__ float bf2f(u16 v){
  u32 u = ((u32)v) << 16;
  return __builtin_bit_cast(float, u);
}
__device__ __forceinline__ bf16x8 ldb8(const u16* p){
  return __builtin_bit_cast(bf16x8, *(const u16x8*)p);
}

// stage 64 rows x 64 bf16 (128B/row) = 8KB. 2 gld16/thread.
__device__ __forceinline__ void stage64(const u16* __restrict__ g0, int stride,
                                        u16* lds0, int tid){
  int w = tid >> 6, lane = tid & 63;
  #pragma unroll
  for (int j = 0; j < 2; j++){
    int slot = j*256 + w*64 + lane;
    int row = slot >> 3, c = slot & 7;
    gld16(g0 + (size_t)row*stride + (SW(c,row) << 3),
          lds0 + (size_t)(j*256 + w*64)*8);
  }
}

// stage 128 rows x 32 bf16 (64B/row) = 8KB. 2 gld16/thread.
__device__ __forceinline__ void stage32(const u16* __restrict__ g0, int stride,
                                        u16* lds0, int tid){
  int w = tid >> 6, lane = tid & 63;
  #pragma unroll
  for (int j = 0; j < 2; j++){
    int slot = j*256 + w*64 + lane;
    int row = slot >> 2, c = slot & 3;
    gld16(g0 + (size_t)row*stride + (SW3(c,row) << 3),
          lds0 + (size_t)(j*256 + w*64)*8);
  }
}

// stage 64 rows x 32 bf16 (64B/row) = 4KB. 1 gld16/thread.
__device__ __forceinline__ void stage32h(const u16* __restrict__ g0, int stride,
                                         u16* lds0, int tid){
  int w = tid >> 6, lane = tid & 63;
  int slot = w*64 + lane;
  int row = slot >> 2, c = slot & 3;
  gld16(g0 + (size_t)row*stride + (SW3(c,row) << 3),
        lds0 + (size_t)(w*64)*8);
}

// ---------------- f32 -> bf16 bulk convert, all three inputs (z picks) -------
__global__ __launch_bounds__(256) void cvt3(const float* __restrict__ s0,
                                            const float* __restrict__ s1,
                                            const float* __restrict__ s2,
                                            u16* __restrict__ d0,
                                            u16* __restrict__ d1,
                                            u16* __restrict__ d2){
  const float* s = blockIdx.z == 0 ? s0 : (blockIdx.z == 1 ? s1 : s2);
  u16*         d = blockIdx.z == 0 ? d0 : (blockIdx.z == 1 ? d1 : d2);
  size_t i = ((size_t)blockIdx.x*256 + threadIdx.x) * 8;
  const float4* p = (const float4*)(s + i);
  float4 x = p[0], y = p[1];
  u16x8 u;
  u[0]=f2bf(x.x); u[1]=f2bf(x.y); u[2]=f2bf(x.z); u[3]=f2bf(x.w);
  u[4]=f2bf(y.x); u[5]=f2bf(y.y); u[6]=f2bf(y.z); u[7]=f2bf(y.w);
  *(u16x8*)(d + i) = u;
}

// ---------------- mask dtype detection + bit-packing (transposed) ------------
__global__ __launch_bounds__(256) void detect_mask(const u32* mw, u32* flag){
  __shared__ int fBig, fFloat;
  if (threadIdx.x == 0){ fBig = 0; fFloat = 0; }
  __syncthreads();
  for (int i = threadIdx.x; i < 4096; i += 256){
    u32 w = mw[i];
    if (w == 0x3f800000u) fFloat = 1;
    else if (w > 1u) fBig = 1;
  }
  __syncthreads();
  if (threadIdx.x == 0) *flag = fFloat ? 2u : (fBig ? 1u : 0u);
}

// e0 = ELEMENT index; packs 32 consecutive mask elements into one bit-word.
__device__ __forceinline__ u32 pack32(const void* mask, u32 f, size_t e0){
  u32 bits = 0;
  if (f == 1u){
    const uchar4* mb = (const uchar4*)((const unsigned char*)mask + e0);
    #pragma unroll
    for (int j = 0; j < 8; j++){
      uchar4 v = mb[j];
      bits |= (v.x?1u:0u) << (4*j)   | (v.y?1u:0u) << (4*j+1)
            | (v.z?1u:0u) << (4*j+2) | (v.w?1u:0u) << (4*j+3);
    }
  } else if (f == 0u){
    const int4* mi = (const int4*)((const int*)mask + e0);
    #pragma unroll
    for (int j = 0; j < 8; j++){
      int4 v = mi[j];
      bits |= (v.x?1u:0u) << (4*j)   | (v.y?1u:0u) << (4*j+1)
            | (v.z?1u:0u) << (4*j+2) | (v.w?1u:0u) << (4*j+3);
    }
  } else {
    const float4* mf = (const float4*)((const float*)mask + e0);
    #pragma unroll
    for (int j = 0; j < 8; j++){
      float4 v = mf[j];
      bits |= (v.x!=0.f?1u:0u) << (4*j)   | (v.y!=0.f?1u:0u) << (4*j+1)
            | (v.z!=0.f?1u:0u) << (4*j+2) | (v.w!=0.f?1u:0u) << (4*j+3);
    }
  }
  return bits;
}

// pmT[b][kw][q]: word (b,kw,q) = mask bits for k = kw*32..+31 of row q.
// 16q x 64kw tile per block, grid (SS/16, BB) = 256 blocks.
__global__ __launch_bounds__(256) void pack_maskT(const void* __restrict__ mask,
                                                  const u32* __restrict__ flag,
                                                  u32* __restrict__ pmT){
  __shared__ u32 tile[16][65];
  u32 f = *flag;
  int b = blockIdx.y;
  int q0 = blockIdx.x * 16;
  int kw = threadIdx.x & 63, qr = threadIdx.x >> 6;   // wave = one qr, kw 0..63
  #pragma unroll
  for (int i = 0; i < 4; i++){
    int row = i*4 + qr;                                // 0..15
    size_t e0 = ((size_t)(b*SS + q0 + row))*SS + kw*32;
    tile[row][kw] = pack32(mask, f, e0);
  }
  __syncthreads();
  int q = threadIdx.x & 15, kw0 = threadIdx.x >> 4;    // kw0 0..15
  #pragma unroll
  for (int i = 0; i < 4; i++){
    int kww = i*16 + kw0;
    pmT[((size_t)b*64 + kww)*SS + q0 + q] = tile[q][kww];
  }
}

// ---------------- weight transpose f32[k][n] -> bf16 Wt[n][k] ----------------
// z==0 (W_q): columns pre-scaled by SCLOG2E so scores come out log2-domain.
__global__ __launch_bounds__(256) void prep_w(const float* __restrict__ W0,
                                              const float* __restrict__ W1,
                                              const float* __restrict__ W2,
                                              const float* __restrict__ W3,
                                              u16* __restrict__ Wt){
  const float* Ws[4] = {W0, W1, W2, W3};
  const float* W = Ws[blockIdx.z];
  float scl = (blockIdx.z == 0) ? SCLOG2E : 1.0f;
  u16* O = Wt + (size_t)blockIdx.z * DD * DD;
  __shared__ float tile[64][65];
  int kb = blockIdx.x * 64, nb = blockIdx.y * 64;
  int col = threadIdx.x & 63, rr = threadIdx.x >> 6;
  #pragma unroll
  for (int i = 0; i < 16; i++){
    int row = i*4 + rr;
    tile[row][col] = W[(size_t)(kb+row)*DD + nb + col];
  }
  __syncthreads();
  #pragma unroll
  for (int i = 0; i < 16; i++){
    int row = i*4 + rr;
    O[(size_t)(nb+row)*DD + kb + col] = f2bf(tile[col][row] * scl);
  }
}

// ---------------- staged GEMM, BK=32: C[M][1024] = A @ Bt^T ------
// 128x128 tile, 4 waves (2x2 of 64x64), 32 KB LDS double-buffered.
// mode 0: bf16 Cb; 1: Cb + f32 permuted [B][H][S][DH]; 2: f32 flat only.
struct GA { const u16* A; const u16* Bt; u16* Cb; float* Co; int mode; };

__global__ __launch_bounds__(256) void gemm32(GA a0, GA a1, GA a2){
  GA ga = blockIdx.z == 0 ? a0 : (blockIdx.z == 1 ? a1 : a2);
  __shared__ u16 As[2][128*32];
  __shared__ u16 Bs[2][128*32];
  int mb = blockIdx.x * 128, nb = blockIdx.y * 128;
  int tid = threadIdx.x, w = tid >> 6, lane = tid & 63, ln = lane & 15, g = lane >> 4;
  int wr = w >> 1, wc = w & 1;
  f32x4 acc[4][4];
  #pragma unroll
  for (int i = 0; i < 4; i++)
    #pragma unroll
    for (int j = 0; j < 4; j++) acc[i][j] = (f32x4){0,0,0,0};

  stage32(ga.A  + (size_t)mb*DD, DD, As[0], tid);
  stage32(ga.Bt + (size_t)nb*DD, DD, Bs[0], tid);
  __syncthreads();
  int buf = 0;
  for (int t = 0; t < 32; t++){
    if (t < 31){
      stage32(ga.A  + (size_t)mb*DD + (t+1)*32, DD, As[buf^1], tid);
      stage32(ga.Bt + (size_t)nb*DD + (t+1)*32, DD, Bs[buf^1], tid);
    }
    bf16x8 av[4], bv[4];
    #pragma unroll
    for (int mf = 0; mf < 4; mf++){
      int row = wr*64 + mf*16 + ln;
      av[mf] = ldb8(&As[buf][row*32 + (SW3(g,row) << 3)]);
    }
    #pragma unroll
    for (int nf = 0; nf < 4; nf++){
      int row = wc*64 + nf*16 + ln;
      bv[nf] = ldb8(&Bs[buf][row*32 + (SW3(g,row) << 3)]);
    }
    #pragma unroll
    for (int mf = 0; mf < 4; mf++)
      #pragma unroll
      for (int nf = 0; nf < 4; nf++)
        acc[mf][nf] = MFMA(av[mf], bv[nf], acc[mf][nf]);
    __syncthreads();
    buf ^= 1;
  }
  #pragma unroll
  for (int mf = 0; mf < 4; mf++){
    #pragma unroll
    for (int nf = 0; nf < 4; nf++){
      #pragma unroll
      for (int r = 0; r < 4; r++){
        int row = mb + wr*64 + mf*16 + g*4 + r;
        int col = nb + wc*64 + nf*16 + ln;
        float v = acc[mf][nf][r];
        if (ga.mode != 2)
          ga.Cb[(size_t)row*DD + col] = f2bf(v);
        if (ga.mode == 1){
          int b_ = row >> 11, s_ = row & (SS-1);
          int h_ = col >> 6,  d_ = col & 63;
          ga.Co[(((size_t)(b_*HH + h_))*SS + s_)*DHH + d_] = v;
        }
        if (ga.mode == 2)
          ga.Co[(size_t)row*DD + col] = v;
      }
    }
  }
}

// ---------------- final GEMM: 64x128 tile, 512 blocks = 2/CU ----------------
// C f32 [M][1024] = A(bf16) @ Bt^T. 4 waves (2x2 of 32x64), BK=32, 24 KB LDS.
__global__ __launch_bounds__(256) void gemm_out(const u16* __restrict__ A,
                                                const u16* __restrict__ Bt,
                                                float* __restrict__ Co){
  __shared__ u16 As[2][64*32];
  __shared__ u16 Bs[2][128*32];
  int mb = blockIdx.x * 64, nb = blockIdx.y * 128;
  int tid = threadIdx.x, w = tid >> 6, lane = tid & 63, ln = lane & 15, g = lane >> 4;
  int wr = w >> 1, wc = w & 1;
  f32x4 acc[2][4];
  #pragma unroll
  for (int i = 0; i < 2; i++)
    #pragma unroll
    for (int j = 0; j < 4; j++) acc[i][j] = (f32x4){0,0,0,0};

  stage32h(A  + (size_t)mb*DD, DD, As[0], tid);
  stage32 (Bt + (size_t)nb*DD, DD, Bs[0], tid);
  __syncthreads();
  int buf = 0;
  for (int t = 0; t < 32; t++){
    if (t < 31){
      stage32h(A  + (size_t)mb*DD + (t+1)*32, DD, As[buf^1], tid);
      stage32 (Bt + (size_t)nb*DD + (t+1)*32, DD, Bs[buf^1], tid);
    }
    bf16x8 av[2], bv[4];
    #pragma unroll
    for (int mf = 0; mf < 2; mf++){
      int row = wr*32 + mf*16 + ln;
      av[mf] = ldb8(&As[buf][row*32 + (SW3(g,row) << 3)]);
    }
    #pragma unroll
    for (int nf = 0; nf < 4; nf++){
      int row = wc*64 + nf*16 + ln;
      bv[nf] = ldb8(&Bs[buf][row*32 + (SW3(g,row) << 3)]);
    }
    #pragma unroll
    for (int mf = 0; mf < 2; mf++)
      #pragma unroll
      for (int nf = 0; nf < 4; nf++)
        acc[mf][nf] = MFMA(av[mf], bv[nf], acc[mf][nf]);
    __syncthreads();
    buf ^= 1;
  }
  #pragma unroll
  for (int mf = 0; mf < 2; mf++)
    #pragma unroll
    for (int nf = 0; nf < 4; nf++)
      #pragma unroll
      for (int r = 0; r < 4; r++){
        int row = mb + wr*32 + mf*16 + g*4 + r;
        int col = nb + wc*64 + nf*16 + ln;
        Co[(size_t)row*DD + col] = acc[mf][nf][r];
      }
}

// ---------------- pass 1: column (over-q) softmax denominators c[k] ----------
// 128-k blocks, 4 waves x 32 k; Q staged in LDS, double-buffered.
// XCD chunk swizzle; transposed mask pmT (coalesced).
__global__ __launch_bounds__(256) void pass1_sum(const u16* __restrict__ Qb,
                                                 const u16* __restrict__ Kb,
                                                 const u32* __restrict__ pmT,
                                                 float* __restrict__ cO){
  __shared__ u16 Qst[2][64*64];
  // bijective XCD swizzle: nwg = 16*16*2 = 512, chunk = 64
  int flat = blockIdx.x + (SS/128)*(blockIdx.y + HH*blockIdx.z);
  int sw = (flat & 7)*64 + (flat >> 3);
  int kblk = (sw & 15) * 128;
  int rest = sw >> 4;
  int h = rest & 15, b = rest >> 4;
  int tid = threadIdx.x, w = tid >> 6, lane = tid & 63, ln = lane & 15, g = lane >> 4;
  bf16x8 kf[2][2];
  #pragma unroll
  for (int f = 0; f < 2; f++){
    const u16* kp = Kb + ((size_t)b*SS + kblk + w*32 + f*16 + ln)*DD + h*DHH + g*8;
    kf[f][0] = ldb8(kp); kf[f][1] = ldb8(kp + 32);
  }
  float cr[2][4] = {{0,0,0,0},{0,0,0,0}};

  stage64(Qb + ((size_t)b*SS)*DD + h*DHH, DD, Qst[0], tid);
  __syncthreads();
  int buf = 0;
  const u32* pmw = pmT + ((size_t)b*64 + (kblk >> 5) + w)*SS;
  for (int t = 0; t < 32; t++){
    if (t < 31) stage64(Qb + ((size_t)b*SS + (t+1)*64)*DD + h*DHH, DD, Qst[buf^1], tid);
    #pragma unroll
    for (int qc = 0; qc < 4; qc++){
      int row = qc*16 + ln;
      bf16x8 b0 = ldb8(&Qst[buf][row*64 + (SW(g,  row) << 3)]);
      bf16x8 b1 = ldb8(&Qst[buf][row*64 + (SW(g+4,row) << 3)]);
      int q = t*64 + qc*16 + ln;
      u32 mw = pmw[q];
      #pragma unroll
      for (int f = 0; f < 2; f++){
        f32x4 sf = {0,0,0,0};
        sf = MFMA(kf[f][0], b0, sf);
        sf = MFMA(kf[f][1], b1, sf);
        #pragma unroll
        for (int r = 0; r < 4; r++){
          float e = __builtin_amdgcn_exp2f(sf[r]);
          cr[f][r] += ((mw >> (f*16 + g*4 + r)) & 1u) ? 0.f : e;
        }
      }
    }
    __syncthreads();
    buf ^= 1;
  }
  #pragma unroll
  for (int f = 0; f < 2; f++)
    #pragma unroll
    for (int r = 0; r < 4; r++){
      #pragma unroll
      for (int msk = 1; msk < 16; msk <<= 1)
        cr[f][r] += __shfl_xor(cr[f][r], msk, 64);
    }
  if (ln == 0){
    #pragma unroll
    for (int f = 0; f < 2; f++)
      #pragma unroll
      for (int r = 0; r < 4; r++)
        cO[((size_t)b*HH + h)*SS + kblk + w*32 + f*16 + g*4 + r] = cr[f][r];
  }
}

// ---------------- scale V by 1/c[k], store transposed+k-permuted Vt ----------
// pi within each 64-k tile matches pass2's in-register P fragment slots:
// pos = (c&32) + ((c>>2)&3)*8 + ((c>>4)&1)*4 + (c&3)
__global__ __launch_bounds__(256) void scale_v(const u16* __restrict__ Vb,
                                               const float* __restrict__ cI,
                                               u16* __restrict__ Vt){
  int b = blockIdx.z, h = blockIdx.y;
  int st = blockIdx.x * 64;
  __shared__ u16 tile[64][72];
  int col = threadIdx.x & 63, rr = threadIdx.x >> 6;
  #pragma unroll
  for (int i = 0; i < 16; i++){
    int row = i*4 + rr;
    int s = st + row;
    float inv = 1.0f / cI[((size_t)b*HH + h)*SS + s];
    float v = bf2f(Vb[((size_t)b*SS + s)*DD + h*DHH + col]);
    tile[row][col] = f2bf(v * inv);
  }
  __syncthreads();
  int pc = (col & 32) + ((col >> 2) & 3)*8 + ((col >> 4) & 1)*4 + (col & 3);
  #pragma unroll
  for (int i = 0; i < 16; i++){
    int row = i*4 + rr;   // row = d index
    Vt[(((size_t)b*HH + h)*DHH + row)*SS + st + pc] = tile[col][row];
  }
}

// ---------------- pass 2: hidden = exp2(S) @ (V/c) ----------------
// 128 q / 4 waves x 32 q (2 frags). Triple-buffered K,V (48 KB LDS).
// Software pipeline: body t = { sync; stage(t+2); QK(t+1)->pkNext; PV(t)<-pkCur }
// so exp2/pack (VALU) of tile t+1 overlaps PV MFMAs of tile t.
// P in registers (S^T = mfma(K,Q)); transposed mask pmT (coalesced, ptr-bumped).
#define P2_QK(PMP, NXT, KP) { \
  u32 _ml[2], _mh[2]; \
  _Pragma("unroll") for (int f = 0; f < 2; f++){ \
    _ml[f] = (PMP)[f*16]; \
    _mh[f] = (PMP)[SS + f*16]; \
  } \
  _Pragma("unroll") for (int kc = 0; kc < 4; kc++){ \
    bf16x8 a0 = ldb8(&KP[koff[kc][0]]); \
    bf16x8 a1 = ldb8(&KP[koff[kc][1]]); \
    _Pragma("unroll") for (int f = 0; f < 2; f++){ \
      f32x4 sf = {0,0,0,0}; \
      sf = MFMA(a0, qf[f][0], sf); \
      sf = MFMA(a1, qf[f][1], sf); \
      u32 mword = (kc < 2) ? _ml[f] : _mh[f]; \
      int msh = (kc & 1) * 16 + g*4; \
      float p0 = ((mword >> (msh+0)) & 1u) ? 0.f : __builtin_amdgcn_exp2f(sf[0]); \
      float p1 = ((mword >> (msh+1)) & 1u) ? 0.f : __builtin_amdgcn_exp2f(sf[1]); \
      float p2 = ((mword >> (msh+2)) & 1u) ? 0.f : __builtin_amdgcn_exp2f(sf[2]); \
      float p3 = ((mword >> (msh+3)) & 1u) ? 0.f : __builtin_amdgcn_exp2f(sf[3]); \
      NXT[f][kc*2]   = (u32)nbf(p0) | ((u32)nbf(p1) << 16); \
      NXT[f][kc*2+1] = (u32)nbf(p2) | ((u32)nbf(p3) << 16); \
    } \
  } }

#define P2_PV(CUR, VP) \
  _Pragma("unroll") for (int kh = 0; kh < 2; kh++){ \
    bf16x8 pa[2]; \
    _Pragma("unroll") for (int f = 0; f < 2; f++) \
      pa[f] = __builtin_bit_cast(bf16x8, \
        (u32x4v){CUR[f][4*kh], CUR[f][4*kh+1], CUR[f][4*kh+2], CUR[f][4*kh+3]}); \
    _Pragma("unroll") for (int df = 0; df < 4; df++){ \
      bf16x8 bv = ldb8(&VP[voff[kh][df]]); \
      _Pragma("unroll") for (int f = 0; f < 2; f++) \
        acc[f][df] = MFMA(pa[f], bv, acc[f][df]); \
    } \
  }

#define P2_BODY(TT, CUR, NXT) \
  __syncthreads(); \
  if ((TT) < 30){ \
    stage64(Kg + (size_t)((TT)+2)*64*DD, DD, K2, tid); \
    stage64(Vth + ((TT)+2)*64,           SS, V2, tid); \
  } \
  if ((TT) < 31) P2_QK(pmq, NXT, K1) \
  P2_PV(CUR, V0) \
  { u16* _tp=K0; K0=K1; K1=K2; K2=_tp; _tp=V0; V0=V1; V1=V2; V2=_tp; pmq += 2*SS; }

__global__ __launch_bounds__(256) void pass2_pv(const u16* __restrict__ Qb,
                                                const u16* __restrict__ Kb,
                                                const u16* __restrict__ Vt,
                                                const u32* __restrict__ pmT,
                                                u16* __restrict__ Hb){
  __shared__ u16 Kst[3][64*64];
  __shared__ u16 Vst[3][64*64];
  // bijective XCD swizzle: nwg = 16*16*2 = 512, chunk = 64
  int flat = blockIdx.x + (SS/128)*(blockIdx.y + HH*blockIdx.z);
  int sw = (flat & 7)*64 + (flat >> 3);
  int qt = (sw & 15) * 128;
  int rest = sw >> 4;
  int h = rest & 15, b = rest >> 4;
  int tid = threadIdx.x, w = tid >> 6, lane = tid & 63, ln = lane & 15, g = lane >> 4;
  bf16x8 qf[2][2];
  #pragma unroll
  for (int f = 0; f < 2; f++){
    const u16* qp = Qb + ((size_t)b*SS + qt + w*32 + f*16 + ln)*DD + h*DHH + g*8;
    qf[f][0] = ldb8(qp); qf[f][1] = ldb8(qp + 32);
  }
  f32x4 acc[2][4];
  #pragma unroll
  for (int f = 0; f < 2; f++)
    #pragma unroll
    for (int d = 0; d < 4; d++) acc[f][d] = (f32x4){0,0,0,0};

  const u16* Kg  = Kb + ((size_t)b*SS)*DD + h*DHH;
  const u16* Vth = Vt + ((size_t)b*HH + h)*DHH*SS;
  const u32* pmq = pmT + (size_t)b*64*SS + (qt + w*32 + ln);

  // t-invariant LDS offsets (hoisted addressing)
  int koff[4][2], voff[2][4];
  #pragma unroll
  for (int kc = 0; kc < 4; kc++){
    int row = kc*16 + ln;
    koff[kc][0] = row*64 + (SW(g,  row) << 3);
    koff[kc][1] = row*64 + (SW(g+4,row) << 3);
  }
  #pragma unroll
  for (int kh = 0; kh < 2; kh++)
    #pragma unroll
    for (int df = 0; df < 4; df++){
      int row = df*16 + ln;
      voff[kh][df] = row*64 + (SW(kh*4+g, row) << 3);
    }

  u16 *K0=&Kst[0][0], *K1=&Kst[1][0], *K2=&Kst[2][0];
  u16 *V0=&Vst[0][0], *V1=&Vst[1][0], *V2=&Vst[2][0];
  u32 pkA[2][8], pkB[2][8];

  stage64(Kg,  DD, K0, tid);
  stage64(Vth, SS, V0, tid);
  __syncthreads();
  P2_QK(pmq, pkA, K0)
  pmq += 2*SS;                   // now points at tile-1 mask words
  stage64(Kg + 64*DD, DD, K1, tid);
  stage64(Vth + 64,   SS, V1, tid);

  #pragma unroll 1
  for (int t = 0; t < 32; t += 2){
    P2_BODY(t,   pkA, pkB)
    P2_BODY(t+1, pkB, pkA)
  }

  #pragma unroll
  for (int f = 0; f < 2; f++)
    #pragma unroll
    for (int df = 0; df < 4; df++)
      #pragma unroll
      for (int r = 0; r < 4; r++){
        int row = qt + w*32 + f*16 + g*4 + r;
        int col = h*DHH + df*16 + ln;
        Hb[((size_t)b*SS + row)*DD + col] = f2bf(acc[f][df][r]);
      }
}

extern "C" void kernel_launch(void* const* d_in, const int* in_sizes, int n_in,
                              void* d_out, int out_size, void* d_ws, size_t ws_size,
                              hipStream_t stream){
  (void)in_sizes; (void)n_in; (void)out_size; (void)ws_size;
  const float* query = (const float*)d_in[0];
  const float* key   = (const float*)d_in[1];
  const float* value = (const float*)d_in[2];
  const void*  mask  = d_in[3];
  const float* W_q = (const float*)d_in[4];
  const float* W_k = (const float*)d_in[5];
  const float* W_v = (const float*)d_in[6];
  const float* W_o = (const float*)d_in[7];

  float* out   = (float*)d_out;
  float* out_h = out;                                  // [B,S,1024]
  float* out_k = out   + (size_t)BB*HH*SS*DHH;         // [B,H,S,DH]
  float* out_v = out_k + (size_t)BB*HH*SS*DHH;

  char* w = (char*)d_ws;
  u16*   Wt  = (u16*)(w);                      // 4 x [1024][1024] bf16 = 8 MB
  u16*   Av  = (u16*)(w + (size_t)( 8u<<20));  // bf16 value input; later Hb
  u16*   Qb  = (u16*)(w + (size_t)(16u<<20));
  u16*   Kb  = (u16*)(w + (size_t)(24u<<20));
  u16*   Vb  = (u16*)(w + (size_t)(32u<<20));
  u16*   Vt  = (u16*)(w + (size_t)(40u<<20));  // [B][H][DH][S] bf16, k-permuted
  float* cS  = (float*)(w + (size_t)(48u<<20));              // 256 KB
  u32*   pmT = (u32*)(w + (size_t)(48u<<20) + (512u<<10));   // 1 MB transposed mask
  u32*   flag= (u32*)(w + (size_t)(48u<<20) + (1664u<<10));
  u16*   Hb  = Av;                             // alias: Av dead after projections
  // bf16 query/key inputs staged inside out_h (dead until final GEMM rewrites it)
  u16*   Aq  = (u16*)out_h;
  u16*   Ak  = Aq + (size_t)BB*SS*DD;

  detect_mask<<<dim3(1), dim3(256), 0, stream>>>((const u32*)mask, flag);
  pack_maskT<<<dim3(SS/16, BB), dim3(256), 0, stream>>>(mask, flag, pmT);
  prep_w<<<dim3(16,16,4), dim3(256), 0, stream>>>(W_q, W_k, W_v, W_o, Wt);

  cvt3<<<dim3(2048,1,3), dim3(256), 0, stream>>>(query, key, value, Aq, Ak, Av);

  GA gq = { Aq, Wt,             Qb, nullptr, 0 };
  GA gk = { Ak, Wt + 1*1048576, Kb, out_k,   1 };
  GA gv = { Av, Wt + 2*1048576, Vb, out_v,   1 };
  gemm32<<<dim3(32,8,3), dim3(256), 0, stream>>>(gq, gk, gv);

  pass1_sum<<<dim3(SS/128, HH, BB), dim3(256), 0, stream>>>(Qb, Kb, pmT, cS);
  scale_v<<<dim3(SS/64, HH, BB), dim3(256), 0, stream>>>(Vb, cS, Vt);
  pass2_pv<<<dim3(SS/128, HH, BB), dim3(256), 0, stream>>>(Qb, Kb, Vt, pmT, Hb);

  gemm_out<<<dim3(64,8), dim3(256), 0, stream>>>(Hb, Wt + 3*1048576, out_h);
}